// Round 9
// baseline (174.883 us; speedup 1.0000x reference)
//
#include <hip/hip_runtime.h>
#include <math.h>

// Problem constants
#define BATCH 16
#define SEQ   4096
#define HIN   128
#define NST   256
#define HOUT  128
#define CL    32              // chunk length for scan
#define NC    (SEQ/CL)        // 128 chunks
#define ROWS  (BATCH*SEQ)     // 65536
#define KTOT  640             // W2 K layout: 4 groups x [Cre64|-Cim64] + D 128

typedef __attribute__((ext_vector_type(8))) short short8;
typedef __attribute__((ext_vector_type(4))) float f32x4;

__device__ inline unsigned short f2bf(float f) {
  union { float f; unsigned u; } v; v.f = f;
  unsigned r = v.u + 0x7FFFu + ((v.u >> 16) & 1u);   // RNE
  return (unsigned short)(r >> 16);
}
__device__ inline float bf2f(unsigned short s) {
  union { unsigned u; float f; } v; v.u = ((unsigned)s) << 16;
  return v.f;
}
__device__ inline float bits2f(unsigned u) {
  union { unsigned u; float f; } v; v.u = u; return v.f;
}

// ------------------------------------------------------------- prep --------
// Wb rows PERMUTED (unchanged): row r: g=r>>7, w=r&127; n = g*64 + (w&63);
//   w<64 -> gamma*B_re[n], else gamma*B_im[n].
// W2 bf16 [128][640], GROUP-INTERLEAVED K: k<512: g=k>>7, kk=k&127,
//   n=g*64+(kk&63); kk<64 -> Cre[o][n], else -Cim[o][n]. k>=512: D[o][k-512].
// (matches k_out3's per-group pre slice [re64|im64])
__global__ __launch_bounds__(256) void k_prep(
    const float* __restrict__ nu_log, const float* __restrict__ theta_log,
    const float* __restrict__ gamma_log,
    const float* __restrict__ Bre, const float* __restrict__ Bim,
    const float* __restrict__ Cre, const float* __restrict__ Cim,
    const float* __restrict__ Dm,
    float* __restrict__ lamre, float* __restrict__ lamim,
    unsigned short* __restrict__ Wb, unsigned short* __restrict__ W2) {
  int idx = blockIdx.x*256 + threadIdx.x;
  if (idx < NST) {
    float lm = expf(-expf(nu_log[idx]));
    float th = expf(theta_log[idx]);
    lamre[idx] = lm * cosf(th);
    lamim[idx] = lm * sinf(th);
  }
  if (idx < 512*HIN) {
    int r = idx >> 7, h = idx & 127;
    int g = r >> 7;
    int w = r & 127;
    int n = g*64 + (w & 63);
    float gm = expf(gamma_log[n]);
    float v = (w < 64) ? Bre[n*HIN + h] : Bim[n*HIN + h];
    Wb[idx] = f2bf(gm * v);
  }
  if (idx < HOUT*KTOT) {
    int o = idx / KTOT, k = idx - o*KTOT;
    float v;
    if (k < 512) {
      int g = k >> 7, kk = k & 127;
      int n = g*64 + (kk & 63);
      v = (kk < 64) ? Cre[o*NST + n] : -Cim[o*NST + n];
    } else {
      v = Dm[o*HIN + (k - 512)];
    }
    W2[idx] = f2bf(v);
  }
}

// ---------------- k1: chunk-carry GEMM (NO preL materialization) -----------
// grid ROWS/64 = 1024. Block: 64 rows (2 chunks) x 512 states.
// Computes only S (chunk carries); local prefixes are RECOMPUTED in k_out3.
// LDS 35.8 KB -> 4 blocks/CU; B staged in k-halves [128][72].
union SharedK1 {
  unsigned short B[128][72];       // 18.4 KB Wb k-half panel
  unsigned short stgb[2][32][136]; // 17.4 KB bu stage (bf16)
};
__global__ __launch_bounds__(256, 4) void k_bu(
    const float* __restrict__ u, const unsigned short* __restrict__ Wb,
    const float* __restrict__ lamre, const float* __restrict__ lamim,
    float* __restrict__ S_re, float* __restrict__ S_im) {
  __shared__ unsigned short Asl[64][136];   // 17.4 KB, resident
  __shared__ SharedK1 sh;
  int tid = threadIdx.x;
  int row0 = blockIdx.x * 64;
  int wid = tid >> 6, lane = tid & 63;
  int lm = lane & 15, lq = lane >> 4;
  int m0 = wid * 16;                  // 16 rows per wave
  int b = row0 >> 12;
  int cbase = (row0 & 4095) >> 5;
  // stage A: 64 rows x 128 f32 -> bf16 (coalesced)
#pragma unroll
  for (int cc = 0; cc < 4; ++cc) {
    int ch = cc*256 + tid;
    int r = ch >> 4, h0 = (ch & 15) * 8;
    const float* src = u + (size_t)(row0 + r)*HIN + h0;
    float4 v0 = *(const float4*)src;
    float4 v1 = *(const float4*)(src + 4);
    unsigned short o[8];
    o[0]=f2bf(v0.x); o[1]=f2bf(v0.y); o[2]=f2bf(v0.z); o[3]=f2bf(v0.w);
    o[4]=f2bf(v1.x); o[5]=f2bf(v1.y); o[6]=f2bf(v1.z); o[7]=f2bf(v1.w);
    *(short8*)&Asl[r][h0] = *(const short8*)o;
  }
  for (int g = 0; g < 4; ++g) {
    f32x4 accB[8];
#pragma unroll
    for (int j = 0; j < 8; ++j) accB[j] = (f32x4)0.f;
    for (int kh = 0; kh < 2; ++kh) {
      __syncthreads();   // A ready / prior scan stgb reads done / kh0 B reads done
#pragma unroll
      for (int cc = 0; cc < 4; ++cc) {
        int ch = cc*256 + tid;
        int r = ch >> 3, h0 = (ch & 7) * 8;
        *(short8*)&sh.B[r][h0] = *(const short8*)&Wb[(size_t)(g*128 + r)*HIN + kh*64 + h0];
      }
      __syncthreads();
#pragma unroll
      for (int ks2 = 0; ks2 < 2; ++ks2) {
        int k0 = (kh*2 + ks2)*32 + lq*8;
        short8 a = *(const short8*)&Asl[m0 + lm][k0];
#pragma unroll
        for (int j = 0; j < 8; ++j) {
          short8 bb = *(const short8*)&sh.B[j*16 + lm][k0 - kh*64];
          accB[j] = __builtin_amdgcn_mfma_f32_16x16x32_bf16(a, bb, accB[j], 0, 0, 0);
        }
      }
    }
    __syncthreads();   // B reads done before stgb overwrite (union)
#pragma unroll
    for (int j = 0; j < 8; ++j)
#pragma unroll
      for (int r = 0; r < 4; ++r) {
        int row = m0 + lq*4 + r;                  // 0..63
        sh.stgb[row >> 5][row & 31][j*16 + lm] = f2bf(accB[j][r]);
      }
    __syncthreads();   // stgb ready
    if (tid < 128) {
      int buf = tid >> 6, nl = tid & 63;
      int ng = g*64 + nl;
      float lr = lamre[ng], li = lamim[ng];
      float rr[CL], ri[CL];
#pragma unroll
      for (int t = 0; t < CL; ++t) {
        rr[t] = bf2f(sh.stgb[buf][t][nl]);
        ri[t] = bf2f(sh.stgb[buf][t][64 + nl]);
      }
      float sr = 0.f, si = 0.f;
#pragma unroll
      for (int t = 0; t < CL; ++t) {
        float nr = lr*sr - li*si + rr[t];
        float ni = lr*si + li*sr + ri[t];
        sr = nr; si = ni;
      }
      int c = cbase + buf;
      int idx = (b*NC + c)*NST + ng;
      S_re[idx] = sr; S_im[idx] = si;
    }
    // next group's kh-top sync covers stgb reads
  }
}

// ---------------- single-kernel scan of chunk carries -> X0 ----------------
// (round-4 text — harness-verified.)
__global__ __launch_bounds__(64) void k_scan(
    const float* __restrict__ S_re, const float* __restrict__ S_im,
    const float* __restrict__ lamre, const float* __restrict__ lamim,
    unsigned* __restrict__ X0Pk) {
  int b = blockIdx.x >> 2;
  int n = (blockIdx.x & 3) * 64 + threadIdx.x;
  float ar = lamre[n], ai = lamim[n];
#pragma unroll
  for (int s = 0; s < 5; ++s) { float nr = ar*ar - ai*ai, ni = 2.f*ar*ai; ar = nr; ai = ni; } // lam^32
  const float* Sr = S_re + (size_t)b*NC*NST + n;
  const float* Si = S_im + (size_t)b*NC*NST + n;
  unsigned* Xp = X0Pk + (size_t)b*NC*NST + n;
  float Are[16], Aim[16], Bre[16], Bim[16];
#pragma unroll
  for (int cc = 0; cc < 16; ++cc) { Are[cc] = Sr[cc*NST]; Aim[cc] = Si[cc*NST]; }
  float xr = 0.f, xi = 0.f;
#pragma unroll
  for (int seg = 0; seg < 8; ++seg) {
    if (seg < 7) {     // prefetch next segment into the other buffer
      const float* pr = Sr + (size_t)(seg+1)*16*NST;
      const float* pi = Si + (size_t)(seg+1)*16*NST;
      if (seg & 1) {
#pragma unroll
        for (int cc = 0; cc < 16; ++cc) { Are[cc] = pr[cc*NST]; Aim[cc] = pi[cc*NST]; }
      } else {
#pragma unroll
        for (int cc = 0; cc < 16; ++cc) { Bre[cc] = pr[cc*NST]; Bim[cc] = pi[cc*NST]; }
      }
    }
#pragma unroll
    for (int cc = 0; cc < 16; ++cc) {
      Xp[(size_t)(seg*16 + cc)*NST] = ((unsigned)f2bf(xi) << 16) | (unsigned)f2bf(xr);
      float cr = (seg & 1) ? Bre[cc] : Are[cc];
      float ci = (seg & 1) ? Bim[cc] : Aim[cc];
      float nr = ar*xr - ai*xi + cr;
      float ni = ar*xi + ai*xr + ci;
      xr = nr; xi = ni;
    }
  }
}

// -------- k_out3: fused recompute-bu + X0-initialized scan + output GEMM ---
// grid ROWS/64 = 1024. Per group g: recompute bu (MFMA, Wb), scan each chunk
// from x0 = X0Pk[chunk] (prefixes INCLUDE the carry — no fix-up), stage pre
// in LDS, multiply against W2's group K-slice. Final slice: u @ D (Asl).
// preL never exists: saves its 128 MB HBM round-trip.
__global__ __launch_bounds__(256, 2) void k_out3(
    const float* __restrict__ u, const unsigned short* __restrict__ Wb,
    const unsigned short* __restrict__ W2,
    const float* __restrict__ lamre, const float* __restrict__ lamim,
    const unsigned* __restrict__ X0Pk,
    float* __restrict__ y) {
  __shared__ unsigned short Asl[64][136];      // 17.4 KB u bf16, resident
  __shared__ unsigned short Bh[128][72];       // 18.4 KB operand k-half panel
  __shared__ unsigned short stgb[2][32][136];  // 17.4 KB bu stage
  __shared__ unsigned short preS[64][136];     // 17.4 KB pre slice [row][re64|im64]
  int tid = threadIdx.x;
  int row0 = blockIdx.x * 64;
  int wid = tid >> 6, lane = tid & 63;
  int lm = lane & 15, lq = lane >> 4;
  int m0 = wid * 16;
  int c0 = row0 >> 5;                 // global chunk index of buf 0
  // stage A (u) once
#pragma unroll
  for (int cc = 0; cc < 4; ++cc) {
    int ch = cc*256 + tid;
    int r = ch >> 4, h0 = (ch & 15) * 8;
    const float* src = u + (size_t)(row0 + r)*HIN + h0;
    float4 v0 = *(const float4*)src;
    float4 v1 = *(const float4*)(src + 4);
    unsigned short o[8];
    o[0]=f2bf(v0.x); o[1]=f2bf(v0.y); o[2]=f2bf(v0.z); o[3]=f2bf(v0.w);
    o[4]=f2bf(v1.x); o[5]=f2bf(v1.y); o[6]=f2bf(v1.z); o[7]=f2bf(v1.w);
    *(short8*)&Asl[r][h0] = *(const short8*)o;
  }
  f32x4 accY[8];
#pragma unroll
  for (int j = 0; j < 8; ++j) accY[j] = (f32x4)0.f;
  for (int g = 0; g < 4; ++g) {
    // --- recompute bu for this state group ---
    f32x4 accB[8];
#pragma unroll
    for (int j = 0; j < 8; ++j) accB[j] = (f32x4)0.f;
    for (int kh = 0; kh < 2; ++kh) {
      __syncthreads();   // A ready / prior Bh readers done
#pragma unroll
      for (int cc = 0; cc < 4; ++cc) {
        int ch = cc*256 + tid;
        int r = ch >> 3, h0 = (ch & 7) * 8;
        *(short8*)&Bh[r][h0] = *(const short8*)&Wb[(size_t)(g*128 + r)*HIN + kh*64 + h0];
      }
      __syncthreads();
#pragma unroll
      for (int ks2 = 0; ks2 < 2; ++ks2) {
        int k0 = (kh*2 + ks2)*32 + lq*8;
        short8 a = *(const short8*)&Asl[m0 + lm][k0];
#pragma unroll
        for (int j = 0; j < 8; ++j) {
          short8 bb = *(const short8*)&Bh[j*16 + lm][k0 - kh*64];
          accB[j] = __builtin_amdgcn_mfma_f32_16x16x32_bf16(a, bb, accB[j], 0, 0, 0);
        }
      }
    }
    // --- stage bu, scan from x0, produce pre slice ---
#pragma unroll
    for (int j = 0; j < 8; ++j)
#pragma unroll
      for (int r = 0; r < 4; ++r) {
        int row = m0 + lq*4 + r;
        stgb[row >> 5][row & 31][j*16 + lm] = f2bf(accB[j][r]);
      }
    __syncthreads();   // stgb ready
    if (tid < 128) {
      int buf = tid >> 6, nl = tid & 63;
      int ng = g*64 + nl;
      float lr = lamre[ng], li = lamim[ng];
      float rr[CL], ri[CL];
#pragma unroll
      for (int t = 0; t < CL; ++t) {
        rr[t] = bf2f(stgb[buf][t][nl]);
        ri[t] = bf2f(stgb[buf][t][64 + nl]);
      }
      unsigned xp = X0Pk[(size_t)(c0 + buf)*NST + ng];
      float sr = bits2f(xp << 16), si = bits2f(xp & 0xFFFF0000u);
#pragma unroll
      for (int t = 0; t < CL; ++t) {
        preS[buf*32 + t][nl]      = f2bf(sr);   // pre BEFORE step t, incl. carry
        preS[buf*32 + t][64 + nl] = f2bf(si);
        float nr = lr*sr - li*si + rr[t];
        float ni = lr*si + li*sr + ri[t];
        sr = nr; si = ni;
      }
    }
    __syncthreads();   // preS ready (also: all bu-MFMA Bh reads long done)
    // --- output GEMM partial: K-slice g*128..g*128+128 of W2 ---
    for (int kh = 0; kh < 2; ++kh) {
      if (kh) __syncthreads();   // kh0 Bh reads done
#pragma unroll
      for (int cc = 0; cc < 4; ++cc) {
        int ch = cc*256 + tid;
        int r = ch >> 3, h0 = (ch & 7) * 8;
        *(short8*)&Bh[r][h0] = *(const short8*)&W2[(size_t)r*KTOT + g*128 + kh*64 + h0];
      }
      __syncthreads();
#pragma unroll
      for (int ks2 = 0; ks2 < 2; ++ks2) {
        int k0 = (kh*2 + ks2)*32 + lq*8;
        short8 a = *(const short8*)&preS[m0 + lm][k0];
#pragma unroll
        for (int j = 0; j < 8; ++j) {
          short8 bb = *(const short8*)&Bh[j*16 + lm][k0 - kh*64];
          accY[j] = __builtin_amdgcn_mfma_f32_16x16x32_bf16(a, bb, accY[j], 0, 0, 0);
        }
      }
    }
  }
  // --- final K-slice: u @ D ---
  for (int kh = 0; kh < 2; ++kh) {
    __syncthreads();   // prior Bh readers done
#pragma unroll
    for (int cc = 0; cc < 4; ++cc) {
      int ch = cc*256 + tid;
      int r = ch >> 3, h0 = (ch & 7) * 8;
      *(short8*)&Bh[r][h0] = *(const short8*)&W2[(size_t)r*KTOT + 512 + kh*64 + h0];
    }
    __syncthreads();
#pragma unroll
    for (int ks2 = 0; ks2 < 2; ++ks2) {
      int k0 = (kh*2 + ks2)*32 + lq*8;
      short8 a = *(const short8*)&Asl[m0 + lm][k0];
#pragma unroll
      for (int j = 0; j < 8; ++j) {
        short8 bb = *(const short8*)&Bh[j*16 + lm][k0 - kh*64];
        accY[j] = __builtin_amdgcn_mfma_f32_16x16x32_bf16(a, bb, accY[j], 0, 0, 0);
      }
    }
  }
  // write y
#pragma unroll
  for (int j = 0; j < 8; ++j)
#pragma unroll
    for (int r = 0; r < 4; ++r)
      y[(size_t)(row0 + m0 + lq*4 + r)*HOUT + j*16 + lm] = accY[j][r];
}

// --------------------------------------------------------------------------
extern "C" void kernel_launch(void* const* d_in, const int* in_sizes, int n_in,
                              void* d_out, int out_size, void* d_ws, size_t ws_size,
                              hipStream_t stream) {
  const float* u         = (const float*)d_in[0];
  const float* nu_log    = (const float*)d_in[1];
  const float* theta_log = (const float*)d_in[2];
  const float* gamma_log = (const float*)d_in[3];
  const float* B_re      = (const float*)d_in[4];
  const float* B_im      = (const float*)d_in[5];
  const float* C_re      = (const float*)d_in[6];
  const float* C_im      = (const float*)d_in[7];
  const float* Dm        = (const float*)d_in[8];
  float* y = (float*)d_out;
  char* ws = (char*)d_ws;

  size_t off = 0;
  float* lamre = (float*)(ws + off);            off += 1024;
  float* lamim = (float*)(ws + off);            off += 1024;
  unsigned short* Wb = (unsigned short*)(ws + off); off += 131072;  // 512x128 bf16
  unsigned short* W2 = (unsigned short*)(ws + off); off += 163840;  // 128x640 bf16
  float* S_re = (float*)(ws + off);             off += 2097152;
  float* S_im = (float*)(ws + off);             off += 2097152;
  unsigned* X0Pk = (unsigned*)(ws + off);       off += 2097152;     // 2048x256 u32

  k_prep<<<320, 256, 0, stream>>>(nu_log, theta_log, gamma_log, B_re, B_im,
                                  C_re, C_im, Dm, lamre, lamim, Wb, W2);
  k_bu<<<ROWS/64, 256, 0, stream>>>(u, Wb, lamre, lamim, S_re, S_im);
  k_scan<<<64, 64, 0, stream>>>(S_re, S_im, lamre, lamim, X0Pk);
  k_out3<<<ROWS/64, 256, 0, stream>>>(u, Wb, W2, lamre, lamim, X0Pk, y);
}

// Round 10
// 171.891 us; speedup vs baseline: 1.0174x; 1.0174x over previous
//
#include <hip/hip_runtime.h>
#include <math.h>

// Problem constants
#define BATCH 16
#define SEQ   4096
#define HIN   128
#define NST   256
#define HOUT  128
#define CL    32              // chunk length for scan
#define NC    (SEQ/CL)        // 128 chunks
#define ROWS  (BATCH*SEQ)     // 65536
#define KTOT  640             // W2 K layout: 4 groups x [Cre64|-Cim64] + D 128

typedef __attribute__((ext_vector_type(8))) short short8;
typedef __attribute__((ext_vector_type(4))) float f32x4;

__device__ inline unsigned short f2bf(float f) {
  union { float f; unsigned u; } v; v.f = f;
  unsigned r = v.u + 0x7FFFu + ((v.u >> 16) & 1u);   // RNE
  return (unsigned short)(r >> 16);
}
__device__ inline float bf2f(unsigned short s) {
  union { unsigned u; float f; } v; v.u = ((unsigned)s) << 16;
  return v.f;
}
__device__ inline float bits2f(unsigned u) {
  union { unsigned u; float f; } v; v.u = u; return v.f;
}

// ------------------------------------------------------------- prep --------
// (verbatim round-9 — harness-verified)
__global__ __launch_bounds__(256) void k_prep(
    const float* __restrict__ nu_log, const float* __restrict__ theta_log,
    const float* __restrict__ gamma_log,
    const float* __restrict__ Bre, const float* __restrict__ Bim,
    const float* __restrict__ Cre, const float* __restrict__ Cim,
    const float* __restrict__ Dm,
    float* __restrict__ lamre, float* __restrict__ lamim,
    unsigned short* __restrict__ Wb, unsigned short* __restrict__ W2) {
  int idx = blockIdx.x*256 + threadIdx.x;
  if (idx < NST) {
    float lm = expf(-expf(nu_log[idx]));
    float th = expf(theta_log[idx]);
    lamre[idx] = lm * cosf(th);
    lamim[idx] = lm * sinf(th);
  }
  if (idx < 512*HIN) {
    int r = idx >> 7, h = idx & 127;
    int g = r >> 7;
    int w = r & 127;
    int n = g*64 + (w & 63);
    float gm = expf(gamma_log[n]);
    float v = (w < 64) ? Bre[n*HIN + h] : Bim[n*HIN + h];
    Wb[idx] = f2bf(gm * v);
  }
  if (idx < HOUT*KTOT) {
    int o = idx / KTOT, k = idx - o*KTOT;
    float v;
    if (k < 512) {
      int g = k >> 7, kk = k & 127;
      int n = g*64 + (kk & 63);
      v = (kk < 64) ? Cre[o*NST + n] : -Cim[o*NST + n];
    } else {
      v = Dm[o*HIN + (k - 512)];
    }
    W2[idx] = f2bf(v);
  }
}

// ---------------- k1: chunk-carry GEMM (NO preL materialization) -----------
// grid ROWS/64 = 1024. v2 schedule: FULL-K Wb panel (one stage/group, was
// two k-halves), flat stg [64][136]. Barriers/block 25 -> 17. LDS 52.2 KB
// -> 3 blocks/CU. Math identical to round-9 (harness-verified).
union SharedK1 {
  unsigned short B[128][136];   // 34.8 KB full-K Wb group panel
  unsigned short stg[64][136];  // 17.4 KB bu stage (bf16)
};
__global__ __launch_bounds__(256, 3) void k_bu(
    const float* __restrict__ u, const unsigned short* __restrict__ Wb,
    const float* __restrict__ lamre, const float* __restrict__ lamim,
    float* __restrict__ S_re, float* __restrict__ S_im) {
  __shared__ unsigned short Asl[64][136];   // 17.4 KB, resident
  __shared__ SharedK1 sh;
  int tid = threadIdx.x;
  int row0 = blockIdx.x * 64;
  int wid = tid >> 6, lane = tid & 63;
  int lm = lane & 15, lq = lane >> 4;
  int m0 = wid * 16;                  // 16 rows per wave
  int b = row0 >> 12;
  int cbase = (row0 & 4095) >> 5;
  // stage A: 64 rows x 128 f32 -> bf16 (coalesced)
#pragma unroll
  for (int cc = 0; cc < 4; ++cc) {
    int ch = cc*256 + tid;
    int r = ch >> 4, h0 = (ch & 15) * 8;
    const float* src = u + (size_t)(row0 + r)*HIN + h0;
    float4 v0 = *(const float4*)src;
    float4 v1 = *(const float4*)(src + 4);
    unsigned short o[8];
    o[0]=f2bf(v0.x); o[1]=f2bf(v0.y); o[2]=f2bf(v0.z); o[3]=f2bf(v0.w);
    o[4]=f2bf(v1.x); o[5]=f2bf(v1.y); o[6]=f2bf(v1.z); o[7]=f2bf(v1.w);
    *(short8*)&Asl[r][h0] = *(const short8*)o;
  }
  for (int g = 0; g < 4; ++g) {
    __syncthreads();   // A ready (g=0) / prior scan's stg reads done (union)
#pragma unroll
    for (int cc = 0; cc < 8; ++cc) {
      int ch = cc*256 + tid;
      int r = ch >> 4, h0 = (ch & 15) * 8;
      *(short8*)&sh.B[r][h0] = *(const short8*)&Wb[(size_t)(g*128 + r)*HIN + h0];
    }
    __syncthreads();
    f32x4 accB[8];
#pragma unroll
    for (int j = 0; j < 8; ++j) accB[j] = (f32x4)0.f;
#pragma unroll
    for (int ks = 0; ks < 4; ++ks) {
      int k0 = ks*32 + lq*8;
      short8 a = *(const short8*)&Asl[m0 + lm][k0];
#pragma unroll
      for (int j = 0; j < 8; ++j) {
        short8 bb = *(const short8*)&sh.B[j*16 + lm][k0];
        accB[j] = __builtin_amdgcn_mfma_f32_16x16x32_bf16(a, bb, accB[j], 0, 0, 0);
      }
    }
    __syncthreads();   // ALL waves' B reads done before stg overwrite (union)
#pragma unroll
    for (int j = 0; j < 8; ++j)
#pragma unroll
      for (int r = 0; r < 4; ++r) {
        int row = m0 + lq*4 + r;                  // 0..63
        sh.stg[row][j*16 + lm] = f2bf(accB[j][r]);
      }
    __syncthreads();   // stg ready
    if (tid < 128) {
      int buf = tid >> 6, nl = tid & 63;
      int ng = g*64 + nl;
      float lr = lamre[ng], li = lamim[ng];
      float rr[CL], ri[CL];
#pragma unroll
      for (int t = 0; t < CL; ++t) {
        rr[t] = bf2f(sh.stg[buf*32 + t][nl]);
        ri[t] = bf2f(sh.stg[buf*32 + t][64 + nl]);
      }
      float sr = 0.f, si = 0.f;
#pragma unroll
      for (int t = 0; t < CL; ++t) {
        float nr = lr*sr - li*si + rr[t];
        float ni = lr*si + li*sr + ri[t];
        sr = nr; si = ni;
      }
      int c = cbase + buf;
      int idx = (b*NC + c)*NST + ng;
      S_re[idx] = sr; S_im[idx] = si;
    }
    // next group's top barrier covers stg reads
  }
}

// ---------------- single-kernel scan of chunk carries -> X0 ----------------
// (verbatim round-4/9 — harness-verified.)
__global__ __launch_bounds__(64) void k_scan(
    const float* __restrict__ S_re, const float* __restrict__ S_im,
    const float* __restrict__ lamre, const float* __restrict__ lamim,
    unsigned* __restrict__ X0Pk) {
  int b = blockIdx.x >> 2;
  int n = (blockIdx.x & 3) * 64 + threadIdx.x;
  float ar = lamre[n], ai = lamim[n];
#pragma unroll
  for (int s = 0; s < 5; ++s) { float nr = ar*ar - ai*ai, ni = 2.f*ar*ai; ar = nr; ai = ni; } // lam^32
  const float* Sr = S_re + (size_t)b*NC*NST + n;
  const float* Si = S_im + (size_t)b*NC*NST + n;
  unsigned* Xp = X0Pk + (size_t)b*NC*NST + n;
  float Are[16], Aim[16], Bre[16], Bim[16];
#pragma unroll
  for (int cc = 0; cc < 16; ++cc) { Are[cc] = Sr[cc*NST]; Aim[cc] = Si[cc*NST]; }
  float xr = 0.f, xi = 0.f;
#pragma unroll
  for (int seg = 0; seg < 8; ++seg) {
    if (seg < 7) {     // prefetch next segment into the other buffer
      const float* pr = Sr + (size_t)(seg+1)*16*NST;
      const float* pi = Si + (size_t)(seg+1)*16*NST;
      if (seg & 1) {
#pragma unroll
        for (int cc = 0; cc < 16; ++cc) { Are[cc] = pr[cc*NST]; Aim[cc] = pi[cc*NST]; }
      } else {
#pragma unroll
        for (int cc = 0; cc < 16; ++cc) { Bre[cc] = pr[cc*NST]; Bim[cc] = pi[cc*NST]; }
      }
    }
#pragma unroll
    for (int cc = 0; cc < 16; ++cc) {
      Xp[(size_t)(seg*16 + cc)*NST] = ((unsigned)f2bf(xi) << 16) | (unsigned)f2bf(xr);
      float cr = (seg & 1) ? Bre[cc] : Are[cc];
      float ci = (seg & 1) ? Bim[cc] : Aim[cc];
      float nr = ar*xr - ai*xi + cr;
      float ni = ar*xi + ai*xr + ci;
      xr = nr; xi = ni;
    }
  }
}

// -------- k_out3 v2: fused recompute + scan + output GEMM, re-scheduled ----
// grid ROWS/64 = 1024, 2 blocks/CU (69.6 KB). Same math as round-9
// (harness-verified); schedule changes only:
//  - full-K panels: one Bh stage per GEMM phase (was two k-halves)
//  - stg/pre SHARED buffer (scan writes pre in place over bu)
//  - scan (threads 0-127) runs CONCURRENTLY with W2 staging (threads 128-255)
// Barriers/block 44 -> 18.
__global__ __launch_bounds__(256, 2) void k_out3(
    const float* __restrict__ u, const unsigned short* __restrict__ Wb,
    const unsigned short* __restrict__ W2,
    const float* __restrict__ lamre, const float* __restrict__ lamim,
    const unsigned* __restrict__ X0Pk,
    float* __restrict__ y) {
  __shared__ unsigned short Asl[64][136];   // 17.4 KB u bf16, resident
  __shared__ unsigned short Bh[128][136];   // 34.8 KB weight panel (full-K)
  __shared__ unsigned short stg[64][136];   // 17.4 KB bu -> pre (in-place)
  int tid = threadIdx.x;
  int row0 = blockIdx.x * 64;
  int wid = tid >> 6, lane = tid & 63;
  int lm = lane & 15, lq = lane >> 4;
  int m0 = wid * 16;
  int c0 = row0 >> 5;                 // global chunk index of buf 0
  // stage A (u) once
#pragma unroll
  for (int cc = 0; cc < 4; ++cc) {
    int ch = cc*256 + tid;
    int r = ch >> 4, h0 = (ch & 15) * 8;
    const float* src = u + (size_t)(row0 + r)*HIN + h0;
    float4 v0 = *(const float4*)src;
    float4 v1 = *(const float4*)(src + 4);
    unsigned short o[8];
    o[0]=f2bf(v0.x); o[1]=f2bf(v0.y); o[2]=f2bf(v0.z); o[3]=f2bf(v0.w);
    o[4]=f2bf(v1.x); o[5]=f2bf(v1.y); o[6]=f2bf(v1.z); o[7]=f2bf(v1.w);
    *(short8*)&Asl[r][h0] = *(const short8*)o;
  }
  f32x4 accY[8];
#pragma unroll
  for (int j = 0; j < 8; ++j) accY[j] = (f32x4)0.f;
  for (int g = 0; g < 4; ++g) {
    __syncthreads();   // A ready (g=0) / prior out-MFMA stg+Bh reads done
    // stage Bh = Wb group panel, full-K
#pragma unroll
    for (int cc = 0; cc < 8; ++cc) {
      int ch = cc*256 + tid;
      int r = ch >> 4, h0 = (ch & 15) * 8;
      *(short8*)&Bh[r][h0] = *(const short8*)&Wb[(size_t)(g*128 + r)*HIN + h0];
    }
    __syncthreads();
    // bu-GEMM
    f32x4 accB[8];
#pragma unroll
    for (int j = 0; j < 8; ++j) accB[j] = (f32x4)0.f;
#pragma unroll
    for (int ks = 0; ks < 4; ++ks) {
      int k0 = ks*32 + lq*8;
      short8 a = *(const short8*)&Asl[m0 + lm][k0];
#pragma unroll
      for (int j = 0; j < 8; ++j) {
        short8 bb = *(const short8*)&Bh[j*16 + lm][k0];
        accB[j] = __builtin_amdgcn_mfma_f32_16x16x32_bf16(a, bb, accB[j], 0, 0, 0);
      }
    }
    // write bu to stg (stg separate from Bh: no race)
#pragma unroll
    for (int j = 0; j < 8; ++j)
#pragma unroll
      for (int r = 0; r < 4; ++r) {
        int row = m0 + lq*4 + r;
        stg[row][j*16 + lm] = f2bf(accB[j][r]);
      }
    __syncthreads();   // stg visible; all Bh(Wb) reads done
    if (tid < 128) {
      // scan from X0; write pre IN PLACE over bu
      int buf = tid >> 6, nl = tid & 63;
      int ng = g*64 + nl;
      float lr = lamre[ng], li = lamim[ng];
      float rr[CL], ri[CL];
#pragma unroll
      for (int t = 0; t < CL; ++t) {
        rr[t] = bf2f(stg[buf*32 + t][nl]);
        ri[t] = bf2f(stg[buf*32 + t][64 + nl]);
      }
      unsigned xp = X0Pk[(size_t)(c0 + buf)*NST + ng];
      float sr = bits2f(xp << 16), si = bits2f(xp & 0xFFFF0000u);
#pragma unroll
      for (int t = 0; t < CL; ++t) {
        stg[buf*32 + t][nl]      = f2bf(sr);   // pre BEFORE step t, incl. carry
        stg[buf*32 + t][64 + nl] = f2bf(si);
        float nr = lr*sr - li*si + rr[t];
        float ni = lr*si + li*sr + ri[t];
        sr = nr; si = ni;
      }
    } else {
      // concurrently stage Bh = W2 group K-slice (128 threads, 16 units each)
#pragma unroll
      for (int cc = 0; cc < 16; ++cc) {
        int ch = cc*128 + (tid - 128);
        int r = ch >> 4, h0 = (ch & 15) * 8;
        *(short8*)&Bh[r][h0] = *(const short8*)&W2[(size_t)r*KTOT + g*128 + h0];
      }
    }
    __syncthreads();   // pre ready + Bh(W2) ready
    // output GEMM partial: K-slice g
#pragma unroll
    for (int ks = 0; ks < 4; ++ks) {
      int k0 = ks*32 + lq*8;
      short8 a = *(const short8*)&stg[m0 + lm][k0];
#pragma unroll
      for (int j = 0; j < 8; ++j) {
        short8 bb = *(const short8*)&Bh[j*16 + lm][k0];
        accY[j] = __builtin_amdgcn_mfma_f32_16x16x32_bf16(a, bb, accY[j], 0, 0, 0);
      }
    }
  }
  // final K-slice: u @ D
  __syncthreads();   // prior out-MFMA Bh reads done
#pragma unroll
  for (int cc = 0; cc < 8; ++cc) {
    int ch = cc*256 + tid;
    int r = ch >> 4, h0 = (ch & 15) * 8;
    *(short8*)&Bh[r][h0] = *(const short8*)&W2[(size_t)r*KTOT + 512 + h0];
  }
  __syncthreads();
#pragma unroll
  for (int ks = 0; ks < 4; ++ks) {
    int k0 = ks*32 + lq*8;
    short8 a = *(const short8*)&Asl[m0 + lm][k0];
#pragma unroll
    for (int j = 0; j < 8; ++j) {
      short8 bb = *(const short8*)&Bh[j*16 + lm][k0];
      accY[j] = __builtin_amdgcn_mfma_f32_16x16x32_bf16(a, bb, accY[j], 0, 0, 0);
    }
  }
  // write y
#pragma unroll
  for (int j = 0; j < 8; ++j)
#pragma unroll
    for (int r = 0; r < 4; ++r)
      y[(size_t)(row0 + m0 + lq*4 + r)*HOUT + j*16 + lm] = accY[j][r];
}

// --------------------------------------------------------------------------
extern "C" void kernel_launch(void* const* d_in, const int* in_sizes, int n_in,
                              void* d_out, int out_size, void* d_ws, size_t ws_size,
                              hipStream_t stream) {
  const float* u         = (const float*)d_in[0];
  const float* nu_log    = (const float*)d_in[1];
  const float* theta_log = (const float*)d_in[2];
  const float* gamma_log = (const float*)d_in[3];
  const float* B_re      = (const float*)d_in[4];
  const float* B_im      = (const float*)d_in[5];
  const float* C_re      = (const float*)d_in[6];
  const float* C_im      = (const float*)d_in[7];
  const float* Dm        = (const float*)d_in[8];
  float* y = (float*)d_out;
  char* ws = (char*)d_ws;

  size_t off = 0;
  float* lamre = (float*)(ws + off);            off += 1024;
  float* lamim = (float*)(ws + off);            off += 1024;
  unsigned short* Wb = (unsigned short*)(ws + off); off += 131072;  // 512x128 bf16
  unsigned short* W2 = (unsigned short*)(ws + off); off += 163840;  // 128x640 bf16
  float* S_re = (float*)(ws + off);             off += 2097152;
  float* S_im = (float*)(ws + off);             off += 2097152;
  unsigned* X0Pk = (unsigned*)(ws + off);       off += 2097152;     // 2048x256 u32

  k_prep<<<320, 256, 0, stream>>>(nu_log, theta_log, gamma_log, B_re, B_im,
                                  C_re, C_im, Dm, lamre, lamim, Wb, W2);
  k_bu<<<ROWS/64, 256, 0, stream>>>(u, Wb, lamre, lamim, S_re, S_im);
  k_scan<<<64, 64, 0, stream>>>(S_re, S_im, lamre, lamim, X0Pk);
  k_out3<<<ROWS/64, 256, 0, stream>>>(u, Wb, W2, lamre, lamim, X0Pk, y);
}

// Round 11
// 163.454 us; speedup vs baseline: 1.0699x; 1.0516x over previous
//
#include <hip/hip_runtime.h>
#include <math.h>

// Problem constants
#define BATCH 16
#define SEQ   4096
#define HIN   128
#define NST   256
#define HOUT  128
#define CL    32              // chunk length for scan
#define NC    (SEQ/CL)        // 128 chunks
#define ROWS  (BATCH*SEQ)     // 65536
#define KTOT  640             // W K layout: 256 re + 256 im + 128 u
#define NPRE  512             // preL row width: [x_re 256 | x_im 256]

typedef __attribute__((ext_vector_type(8))) short short8;
typedef __attribute__((ext_vector_type(4))) float f32x4;

__device__ inline unsigned short f2bf(float f) {
  union { float f; unsigned u; } v; v.f = f;
  unsigned r = v.u + 0x7FFFu + ((v.u >> 16) & 1u);   // RNE
  return (unsigned short)(r >> 16);
}
__device__ inline float bf2f(unsigned short s) {
  union { unsigned u; float f; } v; v.u = ((unsigned)s) << 16;
  return v.f;
}
__device__ inline float bits2f(unsigned u) {
  union { unsigned u; float f; } v; v.u = u; return v.f;
}

// ------------------------------------------------------------- prep --------
// Wb rows PERMUTED: row r: g=r>>7, w=r&127; n = g*64 + (w&63);
//   w<64 -> gamma*B_re[n], else gamma*B_im[n].
// W = [C_re | -C_im | D] bf16 [128][640].
// lamPk[j][n] = packed bf16 (re lo, im hi) of lambda_n^j, j=0..31.
__global__ __launch_bounds__(256) void k_prep(
    const float* __restrict__ nu_log, const float* __restrict__ theta_log,
    const float* __restrict__ gamma_log,
    const float* __restrict__ Bre, const float* __restrict__ Bim,
    const float* __restrict__ Cre, const float* __restrict__ Cim,
    const float* __restrict__ Dm,
    float* __restrict__ lamre, float* __restrict__ lamim,
    unsigned* __restrict__ lamPk,
    unsigned short* __restrict__ Wb, unsigned short* __restrict__ W) {
  int idx = blockIdx.x*256 + threadIdx.x;
  if (idx < NST) {
    float lm = expf(-expf(nu_log[idx]));
    float th = expf(theta_log[idx]);
    float lr = lm * cosf(th), li = lm * sinf(th);
    lamre[idx] = lr; lamim[idx] = li;
    float pr = 1.f, pi = 0.f;
    for (int j = 0; j < CL; ++j) {
      lamPk[j*NST + idx] = ((unsigned)f2bf(pi) << 16) | (unsigned)f2bf(pr);
      float nr = pr*lr - pi*li;
      float ni = pr*li + pi*lr;
      pr = nr; pi = ni;
    }
  }
  if (idx < 512*HIN) {
    int r = idx >> 7, h = idx & 127;
    int g = r >> 7;
    int w = r & 127;
    int n = g*64 + (w & 63);
    float gm = expf(gamma_log[n]);
    float v = (w < 64) ? Bre[n*HIN + h] : Bim[n*HIN + h];
    Wb[idx] = f2bf(gm * v);
  }
  if (idx < HOUT*KTOT) {
    int o = idx / KTOT, k = idx - o*KTOT;
    float v;
    if (k < NST)        v =  Cre[o*NST + k];
    else if (k < 2*NST) v = -Cim[o*NST + (k - NST)];
    else                v =  Dm[o*HIN + (k - 2*NST)];
    W[idx] = f2bf(v);
  }
}

// -------- bu GEMM (MFMA) + fused local-prefix + chunk-carry epilogue -------
// (verbatim round-7 text — harness-verified at 162.4 us total.)
// grid ROWS/128 = 512. Block: 128 rows x 512 cols (4 col-groups).
// Epilogue: scan writes bf16 prefixes back into the dead LDS staging buffer;
// cooperative coalesced short8 store moves them to preL (128-B runs).
union SharedBu {
  unsigned short B[128][136];      // 34.8 KB group staging
  unsigned short stgb[2][32][136]; // 17.4 KB carry stage (bf16, 16B-aligned rows)
};
__global__ __launch_bounds__(256) void k_bu(
    const float* __restrict__ u, const unsigned short* __restrict__ Wb,
    const float* __restrict__ lamre, const float* __restrict__ lamim,
    unsigned short* __restrict__ preL,
    float* __restrict__ S_re, float* __restrict__ S_im) {
  __shared__ unsigned short Asl[128][136];   // resident whole kernel
  __shared__ SharedBu sh;
  int tid = threadIdx.x;
  int row0 = blockIdx.x * 128;
  int wid = tid >> 6, lane = tid & 63;
  int lm = lane & 15, lq = lane >> 4;
  int m0 = (wid >> 1) * 64, n0 = (wid & 1) * 64;
  int b = row0 >> 12;                 // / SEQ
  int cbase = (row0 & 4095) >> 5;     // / CL
  // stage A: 128 rows x 128 f32 -> bf16
#pragma unroll
  for (int cc = 0; cc < 8; ++cc) {
    int ch = cc*256 + tid;
    int r = ch >> 4, h0 = (ch & 15) * 8;
    const float* src = u + (size_t)(row0 + r)*HIN + h0;
    float4 v0 = *(const float4*)src;
    float4 v1 = *(const float4*)(src + 4);
    unsigned short o[8];
    o[0]=f2bf(v0.x); o[1]=f2bf(v0.y); o[2]=f2bf(v0.z); o[3]=f2bf(v0.w);
    o[4]=f2bf(v1.x); o[5]=f2bf(v1.y); o[6]=f2bf(v1.z); o[7]=f2bf(v1.w);
    *(short8*)&Asl[r][h0] = *(const short8*)o;
  }
  for (int g = 0; g < 4; ++g) {
    __syncthreads();    // A ready (g=0) / prior coop-store reads done (g>0)
#pragma unroll
    for (int cc = 0; cc < 8; ++cc) {
      int ch = cc*256 + tid;
      int r = ch >> 4, h0 = (ch & 15) * 8;
      *(short8*)&sh.B[r][h0] = *(const short8*)&Wb[(size_t)(g*128 + r)*HIN + h0];
    }
    __syncthreads();
    f32x4 acc[4][4];
#pragma unroll
    for (int i = 0; i < 4; ++i)
#pragma unroll
      for (int j = 0; j < 4; ++j) acc[i][j] = (f32x4)0.f;
#pragma unroll
    for (int ks = 0; ks < 4; ++ks) {
      int k0 = ks*32 + lq*8;
      short8 a[4], bb[4];
#pragma unroll
      for (int i = 0; i < 4; ++i) a[i] = *(const short8*)&Asl[m0 + i*16 + lm][k0];
#pragma unroll
      for (int j = 0; j < 4; ++j) bb[j] = *(const short8*)&sh.B[n0 + j*16 + lm][k0];
#pragma unroll
      for (int i = 0; i < 4; ++i)
#pragma unroll
        for (int j = 0; j < 4; ++j)
          acc[i][j] = __builtin_amdgcn_mfma_f32_16x16x32_bf16(a[i], bb[j], acc[i][j], 0, 0, 0);
    }
    // epilogue: per chunk-pair p: stage acc (bf16) -> scan in-registers,
    // prefixes written back to stgb -> cooperative coalesced store to preL.
    for (int p = 0; p < 2; ++p) {
      __syncthreads();   // B reads done (p=0) / prior coop-store reads done (p=1)
#pragma unroll
      for (int ii = 0; ii < 2; ++ii) {
        int i = 2*p + ii;
#pragma unroll
        for (int j = 0; j < 4; ++j)
#pragma unroll
          for (int r = 0; r < 4; ++r) {
            int trow = ii*16 + lq*4 + r;            // 0..31 within chunk
            sh.stgb[wid >> 1][trow][n0 + j*16 + lm] = f2bf(acc[i][j][r]);
          }
      }
      __syncthreads();   // stgb (bu values) ready
      if (tid < 128) {
        int buf = tid >> 6, nl = tid & 63;
        int ng = g*64 + nl;
        float lr = lamre[ng], li = lamim[ng];
        float rr[CL], ri[CL];
#pragma unroll
        for (int t = 0; t < CL; ++t) {
          rr[t] = bf2f(sh.stgb[buf][t][nl]);
          ri[t] = bf2f(sh.stgb[buf][t][64 + nl]);
        }
        float sr = 0.f, si = 0.f;
#pragma unroll
        for (int t = 0; t < CL; ++t) {
          sh.stgb[buf][t][nl]      = f2bf(sr);   // prefix BEFORE step t
          sh.stgb[buf][t][64 + nl] = f2bf(si);
          float nr = lr*sr - li*si + rr[t];
          float ni = lr*si + li*sr + ri[t];
          sr = nr; si = ni;
        }
        int c = cbase + buf*2 + p;
        int idx = (b*NC + c)*NST + ng;
        S_re[idx] = sr; S_im[idx] = si;
      }
      __syncthreads();   // prefixes ready
      // cooperative coalesced store: 2 chunks x 32 rows x (64 re + 64 im)
      // = 1024 short8 units; 4 per thread; 128-B contiguous runs in preL.
#pragma unroll
      for (int q = 0; q < 4; ++q) {
        int uidx = q*256 + tid;            // 0..1023
        int buf = uidx >> 9;
        int rem = uidx & 511;
        int t   = rem >> 4;
        int seg = rem & 15;
        int im  = seg >> 3;                // 0 = re, 1 = im
        int c0  = (seg & 7)*8 + im*64;     // src col in stgb
        int row = row0 + buf*64 + p*32 + t;
        int dcol = im*256 + g*64 + (seg & 7)*8;
        *(short8*)&preL[(size_t)row*NPRE + dcol] = *(const short8*)&sh.stgb[buf][t][c0];
      }
    }
  }
}

// ---------------- single-kernel scan of chunk carries -> X0 ----------------
// (verbatim round-4/7 text — harness-verified.)
__global__ __launch_bounds__(64) void k_scan(
    const float* __restrict__ S_re, const float* __restrict__ S_im,
    const float* __restrict__ lamre, const float* __restrict__ lamim,
    unsigned* __restrict__ X0Pk) {
  int b = blockIdx.x >> 2;
  int n = (blockIdx.x & 3) * 64 + threadIdx.x;
  float ar = lamre[n], ai = lamim[n];
#pragma unroll
  for (int s = 0; s < 5; ++s) { float nr = ar*ar - ai*ai, ni = 2.f*ar*ai; ar = nr; ai = ni; } // lam^32
  const float* Sr = S_re + (size_t)b*NC*NST + n;
  const float* Si = S_im + (size_t)b*NC*NST + n;
  unsigned* Xp = X0Pk + (size_t)b*NC*NST + n;
  float Are[16], Aim[16], Bre[16], Bim[16];
#pragma unroll
  for (int cc = 0; cc < 16; ++cc) { Are[cc] = Sr[cc*NST]; Aim[cc] = Si[cc*NST]; }
  float xr = 0.f, xi = 0.f;
#pragma unroll
  for (int seg = 0; seg < 8; ++seg) {
    if (seg < 7) {     // prefetch next segment into the other buffer
      const float* pr = Sr + (size_t)(seg+1)*16*NST;
      const float* pi = Si + (size_t)(seg+1)*16*NST;
      if (seg & 1) {
#pragma unroll
        for (int cc = 0; cc < 16; ++cc) { Are[cc] = pr[cc*NST]; Aim[cc] = pi[cc*NST]; }
      } else {
#pragma unroll
        for (int cc = 0; cc < 16; ++cc) { Bre[cc] = pr[cc*NST]; Bim[cc] = pi[cc*NST]; }
      }
    }
#pragma unroll
    for (int cc = 0; cc < 16; ++cc) {
      Xp[(size_t)(seg*16 + cc)*NST] = ((unsigned)f2bf(xi) << 16) | (unsigned)f2bf(xr);
      float cr = (seg & 1) ? Bre[cc] : Are[cc];
      float ci = (seg & 1) ? Bim[cc] : Aim[cc];
      float nr = ar*xr - ai*xi + cr;
      float ni = ar*xi + ai*xr + ci;
      xr = nr; xi = ni;
    }
  }
}

// -------------- output GEMM: LDS-staged A with fix-up at staging -----------
// Round-3 structure (harness-verified at 162.4 total). ONE change: the
// A-path (preL gather + fix-up) issues BEFORE B-staging each s-iteration —
// A has the longest chain (global load -> fix-up VALU -> LDS write), so
// issuing it first lets B's loads/LDS-writes overlap A's load latency.
// Same barriers protect both stages; no layout or math change.
__global__ __launch_bounds__(256) void k_out2(
    const unsigned short* __restrict__ preL, const float* __restrict__ u,
    const unsigned short* __restrict__ W,
    const unsigned* __restrict__ lamPk, const unsigned* __restrict__ X0Pk,
    float* __restrict__ y) {
  __shared__ unsigned short Asl[128][136];
  __shared__ unsigned short Bsl[128][136];
  int tid = threadIdx.x;
  int row0 = blockIdx.x * 128;
  int wid = tid >> 6, lane = tid & 63;
  int lm = lane & 15, lq = lane >> 4;
  int m0 = wid * 32;
  f32x4 acc[2][8];
#pragma unroll
  for (int i = 0; i < 2; ++i)
#pragma unroll
    for (int j = 0; j < 8; ++j) acc[i][j] = (f32x4)0.f;
  for (int s = 0; s < 5; ++s) {
    __syncthreads();   // prior MFMA LDS reads done before restage
    // stage A FIRST: 128 rows x 128 cols, coalesced, fix-up applied inline
    if (s < 4) {
#pragma unroll
      for (int cc = 0; cc < 8; ++cc) {
        int ch = cc*256 + tid;
        int r = ch >> 4, h0 = (ch & 15) * 8;
        int grow = row0 + r;
        int j32 = r & 31;            // row0 % 128 == 0
        int cidx = grow >> 5;
        int n = ((s & 1) << 7) + h0; // state index of first element
        short8 loc = *(const short8*)&preL[(size_t)grow*NPRE + s*128 + h0];
        uint4 lp0 = *(const uint4*)&lamPk[j32*NST + n];
        uint4 lp1 = *(const uint4*)&lamPk[j32*NST + n + 4];
        uint4 xp0 = *(const uint4*)&X0Pk[(size_t)cidx*NST + n];
        uint4 xp1 = *(const uint4*)&X0Pk[(size_t)cidx*NST + n + 4];
        unsigned lps[8] = {lp0.x, lp0.y, lp0.z, lp0.w, lp1.x, lp1.y, lp1.z, lp1.w};
        unsigned xps[8] = {xp0.x, xp0.y, xp0.z, xp0.w, xp1.x, xp1.y, xp1.z, xp1.w};
        unsigned short o[8];
#pragma unroll
        for (int e = 0; e < 8; ++e) {
          float lr = bits2f(lps[e] << 16);
          float li = bits2f(lps[e] & 0xFFFF0000u);
          float xr = bits2f(xps[e] << 16);
          float xi = bits2f(xps[e] & 0xFFFF0000u);
          float lv = bf2f((unsigned short)loc[e]);
          float v = (s < 2) ? (lv + lr*xr - li*xi)
                            : (lv + lr*xi + li*xr);
          o[e] = f2bf(v);
        }
        *(short8*)&Asl[r][h0] = *(const short8*)o;
      }
    } else {
#pragma unroll
      for (int cc = 0; cc < 8; ++cc) {
        int ch = cc*256 + tid;
        int r = ch >> 4, h0 = (ch & 15) * 8;
        const float* src = u + (size_t)(row0 + r)*HIN + h0;
        float4 v0 = *(const float4*)src;
        float4 v1 = *(const float4*)(src + 4);
        unsigned short o[8];
        o[0]=f2bf(v0.x); o[1]=f2bf(v0.y); o[2]=f2bf(v0.z); o[3]=f2bf(v0.w);
        o[4]=f2bf(v1.x); o[5]=f2bf(v1.y); o[6]=f2bf(v1.z); o[7]=f2bf(v1.w);
        *(short8*)&Asl[r][h0] = *(const short8*)o;
      }
    }
    // stage B second: W[:, s*128 .. s*128+128)
#pragma unroll
    for (int cc = 0; cc < 8; ++cc) {
      int ch = cc*256 + tid;
      int r = ch >> 4, h0 = (ch & 15) * 8;
      *(short8*)&Bsl[r][h0] = *(const short8*)&W[(size_t)r*KTOT + s*128 + h0];
    }
    __syncthreads();
#pragma unroll
    for (int ks = 0; ks < 4; ++ks) {
      int k0 = ks*32 + lq*8;
      short8 a[2], bb[8];
#pragma unroll
      for (int i = 0; i < 2; ++i) a[i] = *(const short8*)&Asl[m0 + i*16 + lm][k0];
#pragma unroll
      for (int j = 0; j < 8; ++j) bb[j] = *(const short8*)&Bsl[j*16 + lm][k0];
#pragma unroll
      for (int i = 0; i < 2; ++i)
#pragma unroll
        for (int j = 0; j < 8; ++j)
          acc[i][j] = __builtin_amdgcn_mfma_f32_16x16x32_bf16(a[i], bb[j], acc[i][j], 0, 0, 0);
    }
  }
#pragma unroll
  for (int i = 0; i < 2; ++i)
#pragma unroll
    for (int j = 0; j < 8; ++j)
#pragma unroll
      for (int r = 0; r < 4; ++r)
        y[(size_t)(row0 + m0 + i*16 + lq*4 + r)*HOUT + j*16 + lm] = acc[i][j][r];
}

// --------------------------------------------------------------------------
extern "C" void kernel_launch(void* const* d_in, const int* in_sizes, int n_in,
                              void* d_out, int out_size, void* d_ws, size_t ws_size,
                              hipStream_t stream) {
  const float* u         = (const float*)d_in[0];
  const float* nu_log    = (const float*)d_in[1];
  const float* theta_log = (const float*)d_in[2];
  const float* gamma_log = (const float*)d_in[3];
  const float* B_re      = (const float*)d_in[4];
  const float* B_im      = (const float*)d_in[5];
  const float* C_re      = (const float*)d_in[6];
  const float* C_im      = (const float*)d_in[7];
  const float* Dm        = (const float*)d_in[8];
  float* y = (float*)d_out;
  char* ws = (char*)d_ws;

  size_t off = 0;
  float* lamre = (float*)(ws + off);            off += 1024;
  float* lamim = (float*)(ws + off);            off += 1024;
  unsigned* lamPk = (unsigned*)(ws + off);      off += 32768;       // 32x256 u32
  unsigned short* Wb = (unsigned short*)(ws + off); off += 131072;  // 512x128 bf16
  unsigned short* W  = (unsigned short*)(ws + off); off += 163840;  // 128x640 bf16
  unsigned short* preL = (unsigned short*)(ws + off); off += (size_t)ROWS*NPRE*2; // 64 MB
  float* S_re = (float*)(ws + off);             off += 2097152;
  float* S_im = (float*)(ws + off);             off += 2097152;
  unsigned* X0Pk = (unsigned*)(ws + off);       off += 2097152;     // 2048x256 u32

  k_prep<<<320, 256, 0, stream>>>(nu_log, theta_log, gamma_log, B_re, B_im,
                                  C_re, C_im, Dm, lamre, lamim, lamPk, Wb, W);
  k_bu<<<ROWS/128, 256, 0, stream>>>(u, Wb, lamre, lamim, preL, S_re, S_im);
  k_scan<<<64, 64, 0, stream>>>(S_re, S_im, lamre, lamim, X0Pk);
  k_out2<<<ROWS/128, 256, 0, stream>>>(preL, u, W, lamPk, X0Pk, y);
}

// Round 12
// 161.230 us; speedup vs baseline: 1.0847x; 1.0138x over previous
//
#include <hip/hip_runtime.h>
#include <math.h>

// Problem constants
#define BATCH 16
#define SEQ   4096
#define HIN   128
#define NST   256
#define HOUT  128
#define CL    32              // chunk length for scan
#define NC    (SEQ/CL)        // 128 chunks
#define ROWS  (BATCH*SEQ)     // 65536
#define KTOT  640             // W K layout: 256 re + 256 im + 128 u
#define NPRE  512             // preL row width: [x_re 256 | x_im 256]

typedef __attribute__((ext_vector_type(8))) short short8;
typedef __attribute__((ext_vector_type(4))) float f32x4;

__device__ inline unsigned short f2bf(float f) {
  union { float f; unsigned u; } v; v.f = f;
  unsigned r = v.u + 0x7FFFu + ((v.u >> 16) & 1u);   // RNE
  return (unsigned short)(r >> 16);
}
__device__ inline float bf2f(unsigned short s) {
  union { unsigned u; float f; } v; v.u = ((unsigned)s) << 16;
  return v.f;
}
__device__ inline float bits2f(unsigned u) {
  union { unsigned u; float f; } v; v.u = u; return v.f;
}

// LDS-only workgroup barrier: waits lgkmcnt(0) (LDS ordering) but does NOT
// drain vmcnt — global stores stay in flight across phases (T4 mechanism).
// Correctness: no in-kernel reader of our global stores; all load->LDS-write
// and LDS-read->store chains are per-thread data-dependent (compiler-waited).
// Compiler fences stop memory ops migrating across the barrier.
__device__ __forceinline__ void bar_lgkm() {
  asm volatile("s_waitcnt lgkmcnt(0)" ::: "memory");
  __builtin_amdgcn_s_barrier();
  asm volatile("" ::: "memory");
}

// ------------------------------------------------------------- prep --------
// Wb rows PERMUTED: row r: g=r>>7, w=r&127; n = g*64 + (w&63);
//   w<64 -> gamma*B_re[n], else gamma*B_im[n].
// W = [C_re | -C_im | D] bf16 [128][640].
// lamPk[j][n] = packed bf16 (re lo, im hi) of lambda_n^j, j=0..31.
__global__ __launch_bounds__(256) void k_prep(
    const float* __restrict__ nu_log, const float* __restrict__ theta_log,
    const float* __restrict__ gamma_log,
    const float* __restrict__ Bre, const float* __restrict__ Bim,
    const float* __restrict__ Cre, const float* __restrict__ Cim,
    const float* __restrict__ Dm,
    float* __restrict__ lamre, float* __restrict__ lamim,
    unsigned* __restrict__ lamPk,
    unsigned short* __restrict__ Wb, unsigned short* __restrict__ W) {
  int idx = blockIdx.x*256 + threadIdx.x;
  if (idx < NST) {
    float lm = expf(-expf(nu_log[idx]));
    float th = expf(theta_log[idx]);
    float lr = lm * cosf(th), li = lm * sinf(th);
    lamre[idx] = lr; lamim[idx] = li;
    float pr = 1.f, pi = 0.f;
    for (int j = 0; j < CL; ++j) {
      lamPk[j*NST + idx] = ((unsigned)f2bf(pi) << 16) | (unsigned)f2bf(pr);
      float nr = pr*lr - pi*li;
      float ni = pr*li + pi*lr;
      pr = nr; pi = ni;
    }
  }
  if (idx < 512*HIN) {
    int r = idx >> 7, h = idx & 127;
    int g = r >> 7;
    int w = r & 127;
    int n = g*64 + (w & 63);
    float gm = expf(gamma_log[n]);
    float v = (w < 64) ? Bre[n*HIN + h] : Bim[n*HIN + h];
    Wb[idx] = f2bf(gm * v);
  }
  if (idx < HOUT*KTOT) {
    int o = idx / KTOT, k = idx - o*KTOT;
    float v;
    if (k < NST)        v =  Cre[o*NST + k];
    else if (k < 2*NST) v = -Cim[o*NST + (k - NST)];
    else                v =  Dm[o*HIN + (k - 2*NST)];
    W[idx] = f2bf(v);
  }
}

// -------- bu GEMM (MFMA) + fused local-prefix + chunk-carry epilogue -------
// Round-7 structure (harness-verified 162.4 total). ONLY change: all
// __syncthreads replaced with bar_lgkm() — the per-phase vmcnt(0) drain of
// the 16 KB coop-store burst was pure stall (~8 drains/block); stores now
// pipeline across phases.
union SharedBu {
  unsigned short B[128][136];      // 34.8 KB group staging
  unsigned short stgb[2][32][136]; // 17.4 KB carry stage (bf16, 16B-aligned rows)
};
__global__ __launch_bounds__(256) void k_bu(
    const float* __restrict__ u, const unsigned short* __restrict__ Wb,
    const float* __restrict__ lamre, const float* __restrict__ lamim,
    unsigned short* __restrict__ preL,
    float* __restrict__ S_re, float* __restrict__ S_im) {
  __shared__ unsigned short Asl[128][136];   // resident whole kernel
  __shared__ SharedBu sh;
  int tid = threadIdx.x;
  int row0 = blockIdx.x * 128;
  int wid = tid >> 6, lane = tid & 63;
  int lm = lane & 15, lq = lane >> 4;
  int m0 = (wid >> 1) * 64, n0 = (wid & 1) * 64;
  int b = row0 >> 12;                 // / SEQ
  int cbase = (row0 & 4095) >> 5;     // / CL
  // stage A: 128 rows x 128 f32 -> bf16
#pragma unroll
  for (int cc = 0; cc < 8; ++cc) {
    int ch = cc*256 + tid;
    int r = ch >> 4, h0 = (ch & 15) * 8;
    const float* src = u + (size_t)(row0 + r)*HIN + h0;
    float4 v0 = *(const float4*)src;
    float4 v1 = *(const float4*)(src + 4);
    unsigned short o[8];
    o[0]=f2bf(v0.x); o[1]=f2bf(v0.y); o[2]=f2bf(v0.z); o[3]=f2bf(v0.w);
    o[4]=f2bf(v1.x); o[5]=f2bf(v1.y); o[6]=f2bf(v1.z); o[7]=f2bf(v1.w);
    *(short8*)&Asl[r][h0] = *(const short8*)o;
  }
  for (int g = 0; g < 4; ++g) {
    bar_lgkm();    // A ready (g=0) / prior coop-store stgb reads done (g>0)
#pragma unroll
    for (int cc = 0; cc < 8; ++cc) {
      int ch = cc*256 + tid;
      int r = ch >> 4, h0 = (ch & 15) * 8;
      *(short8*)&sh.B[r][h0] = *(const short8*)&Wb[(size_t)(g*128 + r)*HIN + h0];
    }
    bar_lgkm();    // B visible to all waves
    f32x4 acc[4][4];
#pragma unroll
    for (int i = 0; i < 4; ++i)
#pragma unroll
      for (int j = 0; j < 4; ++j) acc[i][j] = (f32x4)0.f;
#pragma unroll
    for (int ks = 0; ks < 4; ++ks) {
      int k0 = ks*32 + lq*8;
      short8 a[4], bb[4];
#pragma unroll
      for (int i = 0; i < 4; ++i) a[i] = *(const short8*)&Asl[m0 + i*16 + lm][k0];
#pragma unroll
      for (int j = 0; j < 4; ++j) bb[j] = *(const short8*)&sh.B[n0 + j*16 + lm][k0];
#pragma unroll
      for (int i = 0; i < 4; ++i)
#pragma unroll
        for (int j = 0; j < 4; ++j)
          acc[i][j] = __builtin_amdgcn_mfma_f32_16x16x32_bf16(a[i], bb[j], acc[i][j], 0, 0, 0);
    }
    // epilogue: per chunk-pair p: stage acc (bf16) -> scan in-registers,
    // prefixes written back to stgb -> cooperative coalesced store to preL.
    for (int p = 0; p < 2; ++p) {
      bar_lgkm();  // B reads done (p=0) / prior coop-store reads done (p=1)
#pragma unroll
      for (int ii = 0; ii < 2; ++ii) {
        int i = 2*p + ii;
#pragma unroll
        for (int j = 0; j < 4; ++j)
#pragma unroll
          for (int r = 0; r < 4; ++r) {
            int trow = ii*16 + lq*4 + r;            // 0..31 within chunk
            sh.stgb[wid >> 1][trow][n0 + j*16 + lm] = f2bf(acc[i][j][r]);
          }
      }
      bar_lgkm();  // stgb (bu values) visible
      if (tid < 128) {
        int buf = tid >> 6, nl = tid & 63;
        int ng = g*64 + nl;
        float lr = lamre[ng], li = lamim[ng];
        float rr[CL], ri[CL];
#pragma unroll
        for (int t = 0; t < CL; ++t) {
          rr[t] = bf2f(sh.stgb[buf][t][nl]);
          ri[t] = bf2f(sh.stgb[buf][t][64 + nl]);
        }
        float sr = 0.f, si = 0.f;
#pragma unroll
        for (int t = 0; t < CL; ++t) {
          sh.stgb[buf][t][nl]      = f2bf(sr);   // prefix BEFORE step t
          sh.stgb[buf][t][64 + nl] = f2bf(si);
          float nr = lr*sr - li*si + rr[t];
          float ni = lr*si + li*sr + ri[t];
          sr = nr; si = ni;
        }
        int c = cbase + buf*2 + p;
        int idx = (b*NC + c)*NST + ng;
        S_re[idx] = sr; S_im[idx] = si;
      }
      bar_lgkm();  // prefixes visible
      // cooperative coalesced store: 2 chunks x 32 rows x (64 re + 64 im)
      // = 1024 short8 units; 4 per thread; 128-B contiguous runs in preL.
      // Stores stay in flight across the next barrier (no vmcnt drain).
#pragma unroll
      for (int q = 0; q < 4; ++q) {
        int uidx = q*256 + tid;            // 0..1023
        int buf = uidx >> 9;
        int rem = uidx & 511;
        int t   = rem >> 4;
        int seg = rem & 15;
        int im  = seg >> 3;                // 0 = re, 1 = im
        int c0  = (seg & 7)*8 + im*64;     // src col in stgb
        int row = row0 + buf*64 + p*32 + t;
        int dcol = im*256 + g*64 + (seg & 7)*8;
        *(short8*)&preL[(size_t)row*NPRE + dcol] = *(const short8*)&sh.stgb[buf][t][c0];
      }
    }
  }
}

// ---------------- single-kernel scan of chunk carries -> X0 ----------------
// (verbatim round-4/7 text — harness-verified.)
__global__ __launch_bounds__(64) void k_scan(
    const float* __restrict__ S_re, const float* __restrict__ S_im,
    const float* __restrict__ lamre, const float* __restrict__ lamim,
    unsigned* __restrict__ X0Pk) {
  int b = blockIdx.x >> 2;
  int n = (blockIdx.x & 3) * 64 + threadIdx.x;
  float ar = lamre[n], ai = lamim[n];
#pragma unroll
  for (int s = 0; s < 5; ++s) { float nr = ar*ar - ai*ai, ni = 2.f*ar*ai; ar = nr; ai = ni; } // lam^32
  const float* Sr = S_re + (size_t)b*NC*NST + n;
  const float* Si = S_im + (size_t)b*NC*NST + n;
  unsigned* Xp = X0Pk + (size_t)b*NC*NST + n;
  float Are[16], Aim[16], Bre[16], Bim[16];
#pragma unroll
  for (int cc = 0; cc < 16; ++cc) { Are[cc] = Sr[cc*NST]; Aim[cc] = Si[cc*NST]; }
  float xr = 0.f, xi = 0.f;
#pragma unroll
  for (int seg = 0; seg < 8; ++seg) {
    if (seg < 7) {     // prefetch next segment into the other buffer
      const float* pr = Sr + (size_t)(seg+1)*16*NST;
      const float* pi = Si + (size_t)(seg+1)*16*NST;
      if (seg & 1) {
#pragma unroll
        for (int cc = 0; cc < 16; ++cc) { Are[cc] = pr[cc*NST]; Aim[cc] = pi[cc*NST]; }
      } else {
#pragma unroll
        for (int cc = 0; cc < 16; ++cc) { Bre[cc] = pr[cc*NST]; Bim[cc] = pi[cc*NST]; }
      }
    }
#pragma unroll
    for (int cc = 0; cc < 16; ++cc) {
      Xp[(size_t)(seg*16 + cc)*NST] = ((unsigned)f2bf(xi) << 16) | (unsigned)f2bf(xr);
      float cr = (seg & 1) ? Bre[cc] : Are[cc];
      float ci = (seg & 1) ? Bim[cc] : Aim[cc];
      float nr = ar*xr - ai*xi + cr;
      float ni = ar*xi + ai*xr + ci;
      xr = nr; xi = ni;
    }
  }
}

// -------------- output GEMM: LDS-staged A with fix-up at staging -----------
// Round-11 structure (A staged first, then B). __syncthreads -> bar_lgkm
// (no vmcnt drain at barriers; staging-load ordering is per-thread data-dep).
__global__ __launch_bounds__(256) void k_out2(
    const unsigned short* __restrict__ preL, const float* __restrict__ u,
    const unsigned short* __restrict__ W,
    const unsigned* __restrict__ lamPk, const unsigned* __restrict__ X0Pk,
    float* __restrict__ y) {
  __shared__ unsigned short Asl[128][136];
  __shared__ unsigned short Bsl[128][136];
  int tid = threadIdx.x;
  int row0 = blockIdx.x * 128;
  int wid = tid >> 6, lane = tid & 63;
  int lm = lane & 15, lq = lane >> 4;
  int m0 = wid * 32;
  f32x4 acc[2][8];
#pragma unroll
  for (int i = 0; i < 2; ++i)
#pragma unroll
    for (int j = 0; j < 8; ++j) acc[i][j] = (f32x4)0.f;
  for (int s = 0; s < 5; ++s) {
    bar_lgkm();   // prior MFMA LDS reads done before restage
    // stage A FIRST: 128 rows x 128 cols, coalesced, fix-up applied inline
    if (s < 4) {
#pragma unroll
      for (int cc = 0; cc < 8; ++cc) {
        int ch = cc*256 + tid;
        int r = ch >> 4, h0 = (ch & 15) * 8;
        int grow = row0 + r;
        int j32 = r & 31;            // row0 % 128 == 0
        int cidx = grow >> 5;
        int n = ((s & 1) << 7) + h0; // state index of first element
        short8 loc = *(const short8*)&preL[(size_t)grow*NPRE + s*128 + h0];
        uint4 lp0 = *(const uint4*)&lamPk[j32*NST + n];
        uint4 lp1 = *(const uint4*)&lamPk[j32*NST + n + 4];
        uint4 xp0 = *(const uint4*)&X0Pk[(size_t)cidx*NST + n];
        uint4 xp1 = *(const uint4*)&X0Pk[(size_t)cidx*NST + n + 4];
        unsigned lps[8] = {lp0.x, lp0.y, lp0.z, lp0.w, lp1.x, lp1.y, lp1.z, lp1.w};
        unsigned xps[8] = {xp0.x, xp0.y, xp0.z, xp0.w, xp1.x, xp1.y, xp1.z, xp1.w};
        unsigned short o[8];
#pragma unroll
        for (int e = 0; e < 8; ++e) {
          float lr = bits2f(lps[e] << 16);
          float li = bits2f(lps[e] & 0xFFFF0000u);
          float xr = bits2f(xps[e] << 16);
          float xi = bits2f(xps[e] & 0xFFFF0000u);
          float lv = bf2f((unsigned short)loc[e]);
          float v = (s < 2) ? (lv + lr*xr - li*xi)
                            : (lv + lr*xi + li*xr);
          o[e] = f2bf(v);
        }
        *(short8*)&Asl[r][h0] = *(const short8*)o;
      }
    } else {
#pragma unroll
      for (int cc = 0; cc < 8; ++cc) {
        int ch = cc*256 + tid;
        int r = ch >> 4, h0 = (ch & 15) * 8;
        const float* src = u + (size_t)(row0 + r)*HIN + h0;
        float4 v0 = *(const float4*)src;
        float4 v1 = *(const float4*)(src + 4);
        unsigned short o[8];
        o[0]=f2bf(v0.x); o[1]=f2bf(v0.y); o[2]=f2bf(v0.z); o[3]=f2bf(v0.w);
        o[4]=f2bf(v1.x); o[5]=f2bf(v1.y); o[6]=f2bf(v1.z); o[7]=f2bf(v1.w);
        *(short8*)&Asl[r][h0] = *(const short8*)o;
      }
    }
    // stage B second: W[:, s*128 .. s*128+128)
#pragma unroll
    for (int cc = 0; cc < 8; ++cc) {
      int ch = cc*256 + tid;
      int r = ch >> 4, h0 = (ch & 15) * 8;
      *(short8*)&Bsl[r][h0] = *(const short8*)&W[(size_t)r*KTOT + s*128 + h0];
    }
    bar_lgkm();   // Asl/Bsl visible
#pragma unroll
    for (int ks = 0; ks < 4; ++ks) {
      int k0 = ks*32 + lq*8;
      short8 a[2], bb[8];
#pragma unroll
      for (int i = 0; i < 2; ++i) a[i] = *(const short8*)&Asl[m0 + i*16 + lm][k0];
#pragma unroll
      for (int j = 0; j < 8; ++j) bb[j] = *(const short8*)&Bsl[j*16 + lm][k0];
#pragma unroll
      for (int i = 0; i < 2; ++i)
#pragma unroll
        for (int j = 0; j < 8; ++j)
          acc[i][j] = __builtin_amdgcn_mfma_f32_16x16x32_bf16(a[i], bb[j], acc[i][j], 0, 0, 0);
    }
  }
#pragma unroll
  for (int i = 0; i < 2; ++i)
#pragma unroll
    for (int j = 0; j < 8; ++j)
#pragma unroll
      for (int r = 0; r < 4; ++r)
        y[(size_t)(row0 + m0 + i*16 + lq*4 + r)*HOUT + j*16 + lm] = acc[i][j][r];
}

// --------------------------------------------------------------------------
extern "C" void kernel_launch(void* const* d_in, const int* in_sizes, int n_in,
                              void* d_out, int out_size, void* d_ws, size_t ws_size,
                              hipStream_t stream) {
  const float* u         = (const float*)d_in[0];
  const float* nu_log    = (const float*)d_in[1];
  const float* theta_log = (const float*)d_in[2];
  const float* gamma_log = (const float*)d_in[3];
  const float* B_re      = (const float*)d_in[4];
  const float* B_im      = (const float*)d_in[5];
  const float* C_re      = (const float*)d_in[6];
  const float* C_im      = (const float*)d_in[7];
  const float* Dm        = (const float*)d_in[8];
  float* y = (float*)d_out;
  char* ws = (char*)d_ws;

  size_t off = 0;
  float* lamre = (float*)(ws + off);            off += 1024;
  float* lamim = (float*)(ws + off);            off += 1024;
  unsigned* lamPk = (unsigned*)(ws + off);      off += 32768;       // 32x256 u32
  unsigned short* Wb = (unsigned short*)(ws + off); off += 131072;  // 512x128 bf16
  unsigned short* W  = (unsigned short*)(ws + off); off += 163840;  // 128x640 bf16
  unsigned short* preL = (unsigned short*)(ws + off); off += (size_t)ROWS*NPRE*2; // 64 MB
  float* S_re = (float*)(ws + off);             off += 2097152;
  float* S_im = (float*)(ws + off);             off += 2097152;
  unsigned* X0Pk = (unsigned*)(ws + off);       off += 2097152;     // 2048x256 u32

  k_prep<<<320, 256, 0, stream>>>(nu_log, theta_log, gamma_log, B_re, B_im,
                                  C_re, C_im, Dm, lamre, lamim, lamPk, Wb, W);
  k_bu<<<ROWS/128, 256, 0, stream>>>(u, Wb, lamre, lamim, preL, S_re, S_im);
  k_scan<<<64, 64, 0, stream>>>(S_re, S_im, lamre, lamim, X0Pk);
  k_out2<<<ROWS/128, 256, 0, stream>>>(preL, u, W, lamPk, X0Pk, y);
}

// Round 13
// 158.448 us; speedup vs baseline: 1.1037x; 1.0176x over previous
//
#include <hip/hip_runtime.h>
#include <math.h>

// Problem constants
#define BATCH 16
#define SEQ   4096
#define HIN   128
#define NST   256
#define HOUT  128
#define CL    32              // chunk length for scan
#define NC    (SEQ/CL)        // 128 chunks
#define ROWS  (BATCH*SEQ)     // 65536
#define KTOT  640             // W K layout: 256 re + 256 im + 128 u
#define NPRE  512             // preL row width: [x_re 256 | x_im 256]

typedef __attribute__((ext_vector_type(8))) short short8;
typedef __attribute__((ext_vector_type(4))) float f32x4;

__device__ inline unsigned short f2bf(float f) {
  union { float f; unsigned u; } v; v.f = f;
  unsigned r = v.u + 0x7FFFu + ((v.u >> 16) & 1u);   // RNE
  return (unsigned short)(r >> 16);
}
// Truncating f32->bf16 (1 instr vs 5): used ONLY in per-element hot paths.
// absmax margin is 5x (0.031 vs 0.15 threshold); truncation ~doubles the
// per-value conversion error, still well inside margin.
__device__ inline unsigned short f2bft(float f) {
  union { float f; unsigned u; } v; v.f = f;
  return (unsigned short)(v.u >> 16);
}
__device__ inline float bf2f(unsigned short s) {
  union { unsigned u; float f; } v; v.u = ((unsigned)s) << 16;
  return v.f;
}
__device__ inline float bits2f(unsigned u) {
  union { unsigned u; float f; } v; v.u = u; return v.f;
}

// LDS-only workgroup barrier: waits lgkmcnt(0) (LDS ordering) but does NOT
// drain vmcnt — global stores stay in flight across phases (T4 mechanism).
__device__ __forceinline__ void bar_lgkm() {
  asm volatile("s_waitcnt lgkmcnt(0)" ::: "memory");
  __builtin_amdgcn_s_barrier();
  asm volatile("" ::: "memory");
}

// ------------------------------------------------------------- prep --------
// (RNE kept: one-time, feeds everything.)
__global__ __launch_bounds__(256) void k_prep(
    const float* __restrict__ nu_log, const float* __restrict__ theta_log,
    const float* __restrict__ gamma_log,
    const float* __restrict__ Bre, const float* __restrict__ Bim,
    const float* __restrict__ Cre, const float* __restrict__ Cim,
    const float* __restrict__ Dm,
    float* __restrict__ lamre, float* __restrict__ lamim,
    unsigned* __restrict__ lamPk,
    unsigned short* __restrict__ Wb, unsigned short* __restrict__ W) {
  int idx = blockIdx.x*256 + threadIdx.x;
  if (idx < NST) {
    float lm = expf(-expf(nu_log[idx]));
    float th = expf(theta_log[idx]);
    float lr = lm * cosf(th), li = lm * sinf(th);
    lamre[idx] = lr; lamim[idx] = li;
    float pr = 1.f, pi = 0.f;
    for (int j = 0; j < CL; ++j) {
      lamPk[j*NST + idx] = ((unsigned)f2bf(pi) << 16) | (unsigned)f2bf(pr);
      float nr = pr*lr - pi*li;
      float ni = pr*li + pi*lr;
      pr = nr; pi = ni;
    }
  }
  if (idx < 512*HIN) {
    int r = idx >> 7, h = idx & 127;
    int g = r >> 7;
    int w = r & 127;
    int n = g*64 + (w & 63);
    float gm = expf(gamma_log[n]);
    float v = (w < 64) ? Bre[n*HIN + h] : Bim[n*HIN + h];
    Wb[idx] = f2bf(gm * v);
  }
  if (idx < HOUT*KTOT) {
    int o = idx / KTOT, k = idx - o*KTOT;
    float v;
    if (k < NST)        v =  Cre[o*NST + k];
    else if (k < 2*NST) v = -Cim[o*NST + (k - NST)];
    else                v =  Dm[o*HIN + (k - 2*NST)];
    W[idx] = f2bf(v);
  }
}

// -------- bu GEMM (MFMA) + fused local-prefix + chunk-carry epilogue -------
// Round-12 structure (best measured 161.2). ONLY change: hot-path f32->bf16
// conversions use f2bft (truncate, 1 instr) — staging VALU is wall time in
// this phase-serialized schedule.
union SharedBu {
  unsigned short B[128][136];      // 34.8 KB group staging
  unsigned short stgb[2][32][136]; // 17.4 KB carry stage (bf16, 16B-aligned rows)
};
__global__ __launch_bounds__(256) void k_bu(
    const float* __restrict__ u, const unsigned short* __restrict__ Wb,
    const float* __restrict__ lamre, const float* __restrict__ lamim,
    unsigned short* __restrict__ preL,
    float* __restrict__ S_re, float* __restrict__ S_im) {
  __shared__ unsigned short Asl[128][136];   // resident whole kernel
  __shared__ SharedBu sh;
  int tid = threadIdx.x;
  int row0 = blockIdx.x * 128;
  int wid = tid >> 6, lane = tid & 63;
  int lm = lane & 15, lq = lane >> 4;
  int m0 = (wid >> 1) * 64, n0 = (wid & 1) * 64;
  int b = row0 >> 12;                 // / SEQ
  int cbase = (row0 & 4095) >> 5;     // / CL
  // stage A: 128 rows x 128 f32 -> bf16 (truncating cvt)
#pragma unroll
  for (int cc = 0; cc < 8; ++cc) {
    int ch = cc*256 + tid;
    int r = ch >> 4, h0 = (ch & 15) * 8;
    const float* src = u + (size_t)(row0 + r)*HIN + h0;
    float4 v0 = *(const float4*)src;
    float4 v1 = *(const float4*)(src + 4);
    unsigned short o[8];
    o[0]=f2bft(v0.x); o[1]=f2bft(v0.y); o[2]=f2bft(v0.z); o[3]=f2bft(v0.w);
    o[4]=f2bft(v1.x); o[5]=f2bft(v1.y); o[6]=f2bft(v1.z); o[7]=f2bft(v1.w);
    *(short8*)&Asl[r][h0] = *(const short8*)o;
  }
  for (int g = 0; g < 4; ++g) {
    bar_lgkm();    // A ready (g=0) / prior coop-store stgb reads done (g>0)
#pragma unroll
    for (int cc = 0; cc < 8; ++cc) {
      int ch = cc*256 + tid;
      int r = ch >> 4, h0 = (ch & 15) * 8;
      *(short8*)&sh.B[r][h0] = *(const short8*)&Wb[(size_t)(g*128 + r)*HIN + h0];
    }
    bar_lgkm();    // B visible to all waves
    f32x4 acc[4][4];
#pragma unroll
    for (int i = 0; i < 4; ++i)
#pragma unroll
      for (int j = 0; j < 4; ++j) acc[i][j] = (f32x4)0.f;
#pragma unroll
    for (int ks = 0; ks < 4; ++ks) {
      int k0 = ks*32 + lq*8;
      short8 a[4], bb[4];
#pragma unroll
      for (int i = 0; i < 4; ++i) a[i] = *(const short8*)&Asl[m0 + i*16 + lm][k0];
#pragma unroll
      for (int j = 0; j < 4; ++j) bb[j] = *(const short8*)&sh.B[n0 + j*16 + lm][k0];
#pragma unroll
      for (int i = 0; i < 4; ++i)
#pragma unroll
        for (int j = 0; j < 4; ++j)
          acc[i][j] = __builtin_amdgcn_mfma_f32_16x16x32_bf16(a[i], bb[j], acc[i][j], 0, 0, 0);
    }
    // epilogue: per chunk-pair p: stage acc (bf16) -> scan in-registers,
    // prefixes written back to stgb -> cooperative coalesced store to preL.
    for (int p = 0; p < 2; ++p) {
      bar_lgkm();  // B reads done (p=0) / prior coop-store reads done (p=1)
#pragma unroll
      for (int ii = 0; ii < 2; ++ii) {
        int i = 2*p + ii;
#pragma unroll
        for (int j = 0; j < 4; ++j)
#pragma unroll
          for (int r = 0; r < 4; ++r) {
            int trow = ii*16 + lq*4 + r;            // 0..31 within chunk
            sh.stgb[wid >> 1][trow][n0 + j*16 + lm] = f2bft(acc[i][j][r]);
          }
      }
      bar_lgkm();  // stgb (bu values) visible
      if (tid < 128) {
        int buf = tid >> 6, nl = tid & 63;
        int ng = g*64 + nl;
        float lr = lamre[ng], li = lamim[ng];
        float rr[CL], ri[CL];
#pragma unroll
        for (int t = 0; t < CL; ++t) {
          rr[t] = bf2f(sh.stgb[buf][t][nl]);
          ri[t] = bf2f(sh.stgb[buf][t][64 + nl]);
        }
        float sr = 0.f, si = 0.f;
#pragma unroll
        for (int t = 0; t < CL; ++t) {
          sh.stgb[buf][t][nl]      = f2bft(sr);   // prefix BEFORE step t
          sh.stgb[buf][t][64 + nl] = f2bft(si);
          float nr = lr*sr - li*si + rr[t];
          float ni = lr*si + li*sr + ri[t];
          sr = nr; si = ni;
        }
        int c = cbase + buf*2 + p;
        int idx = (b*NC + c)*NST + ng;
        S_re[idx] = sr; S_im[idx] = si;
      }
      bar_lgkm();  // prefixes visible
      // cooperative coalesced store: 1024 short8 units; 4/thread; 128-B runs.
#pragma unroll
      for (int q = 0; q < 4; ++q) {
        int uidx = q*256 + tid;            // 0..1023
        int buf = uidx >> 9;
        int rem = uidx & 511;
        int t   = rem >> 4;
        int seg = rem & 15;
        int im  = seg >> 3;                // 0 = re, 1 = im
        int c0  = (seg & 7)*8 + im*64;     // src col in stgb
        int row = row0 + buf*64 + p*32 + t;
        int dcol = im*256 + g*64 + (seg & 7)*8;
        *(short8*)&preL[(size_t)row*NPRE + dcol] = *(const short8*)&sh.stgb[buf][t][c0];
      }
    }
  }
}

// ---------------- single-kernel scan of chunk carries -> X0 ----------------
// (verbatim round-4/7 text — harness-verified; RNE kept, one-time.)
__global__ __launch_bounds__(64) void k_scan(
    const float* __restrict__ S_re, const float* __restrict__ S_im,
    const float* __restrict__ lamre, const float* __restrict__ lamim,
    unsigned* __restrict__ X0Pk) {
  int b = blockIdx.x >> 2;
  int n = (blockIdx.x & 3) * 64 + threadIdx.x;
  float ar = lamre[n], ai = lamim[n];
#pragma unroll
  for (int s = 0; s < 5; ++s) { float nr = ar*ar - ai*ai, ni = 2.f*ar*ai; ar = nr; ai = ni; } // lam^32
  const float* Sr = S_re + (size_t)b*NC*NST + n;
  const float* Si = S_im + (size_t)b*NC*NST + n;
  unsigned* Xp = X0Pk + (size_t)b*NC*NST + n;
  float Are[16], Aim[16], Bre[16], Bim[16];
#pragma unroll
  for (int cc = 0; cc < 16; ++cc) { Are[cc] = Sr[cc*NST]; Aim[cc] = Si[cc*NST]; }
  float xr = 0.f, xi = 0.f;
#pragma unroll
  for (int seg = 0; seg < 8; ++seg) {
    if (seg < 7) {     // prefetch next segment into the other buffer
      const float* pr = Sr + (size_t)(seg+1)*16*NST;
      const float* pi = Si + (size_t)(seg+1)*16*NST;
      if (seg & 1) {
#pragma unroll
        for (int cc = 0; cc < 16; ++cc) { Are[cc] = pr[cc*NST]; Aim[cc] = pi[cc*NST]; }
      } else {
#pragma unroll
        for (int cc = 0; cc < 16; ++cc) { Bre[cc] = pr[cc*NST]; Bim[cc] = pi[cc*NST]; }
      }
    }
#pragma unroll
    for (int cc = 0; cc < 16; ++cc) {
      Xp[(size_t)(seg*16 + cc)*NST] = ((unsigned)f2bf(xi) << 16) | (unsigned)f2bf(xr);
      float cr = (seg & 1) ? Bre[cc] : Are[cc];
      float ci = (seg & 1) ? Bim[cc] : Aim[cc];
      float nr = ar*xr - ai*xi + cr;
      float ni = ar*xi + ai*xr + ci;
      xr = nr; xi = ni;
    }
  }
}

// -------------- output GEMM: LDS-staged A with fix-up at staging -----------
// Round-12 structure. ONLY change: fix-up + u-conversion use f2bft
// (truncate) — removes ~4 VALU ops per staged element from the phase
// critical path.
__global__ __launch_bounds__(256) void k_out2(
    const unsigned short* __restrict__ preL, const float* __restrict__ u,
    const unsigned short* __restrict__ W,
    const unsigned* __restrict__ lamPk, const unsigned* __restrict__ X0Pk,
    float* __restrict__ y) {
  __shared__ unsigned short Asl[128][136];
  __shared__ unsigned short Bsl[128][136];
  int tid = threadIdx.x;
  int row0 = blockIdx.x * 128;
  int wid = tid >> 6, lane = tid & 63;
  int lm = lane & 15, lq = lane >> 4;
  int m0 = wid * 32;
  f32x4 acc[2][8];
#pragma unroll
  for (int i = 0; i < 2; ++i)
#pragma unroll
    for (int j = 0; j < 8; ++j) acc[i][j] = (f32x4)0.f;
  for (int s = 0; s < 5; ++s) {
    bar_lgkm();   // prior MFMA LDS reads done before restage
    // stage A FIRST: 128 rows x 128 cols, coalesced, fix-up applied inline
    if (s < 4) {
#pragma unroll
      for (int cc = 0; cc < 8; ++cc) {
        int ch = cc*256 + tid;
        int r = ch >> 4, h0 = (ch & 15) * 8;
        int grow = row0 + r;
        int j32 = r & 31;            // row0 % 128 == 0
        int cidx = grow >> 5;
        int n = ((s & 1) << 7) + h0; // state index of first element
        short8 loc = *(const short8*)&preL[(size_t)grow*NPRE + s*128 + h0];
        uint4 lp0 = *(const uint4*)&lamPk[j32*NST + n];
        uint4 lp1 = *(const uint4*)&lamPk[j32*NST + n + 4];
        uint4 xp0 = *(const uint4*)&X0Pk[(size_t)cidx*NST + n];
        uint4 xp1 = *(const uint4*)&X0Pk[(size_t)cidx*NST + n + 4];
        unsigned lps[8] = {lp0.x, lp0.y, lp0.z, lp0.w, lp1.x, lp1.y, lp1.z, lp1.w};
        unsigned xps[8] = {xp0.x, xp0.y, xp0.z, xp0.w, xp1.x, xp1.y, xp1.z, xp1.w};
        unsigned short o[8];
#pragma unroll
        for (int e = 0; e < 8; ++e) {
          float lr = bits2f(lps[e] << 16);
          float li = bits2f(lps[e] & 0xFFFF0000u);
          float xr = bits2f(xps[e] << 16);
          float xi = bits2f(xps[e] & 0xFFFF0000u);
          float lv = bf2f((unsigned short)loc[e]);
          float v = (s < 2) ? (lv + lr*xr - li*xi)
                            : (lv + lr*xi + li*xr);
          o[e] = f2bft(v);
        }
        *(short8*)&Asl[r][h0] = *(const short8*)o;
      }
    } else {
#pragma unroll
      for (int cc = 0; cc < 8; ++cc) {
        int ch = cc*256 + tid;
        int r = ch >> 4, h0 = (ch & 15) * 8;
        const float* src = u + (size_t)(row0 + r)*HIN + h0;
        float4 v0 = *(const float4*)src;
        float4 v1 = *(const float4*)(src + 4);
        unsigned short o[8];
        o[0]=f2bft(v0.x); o[1]=f2bft(v0.y); o[2]=f2bft(v0.z); o[3]=f2bft(v0.w);
        o[4]=f2bft(v1.x); o[5]=f2bft(v1.y); o[6]=f2bft(v1.z); o[7]=f2bft(v1.w);
        *(short8*)&Asl[r][h0] = *(const short8*)o;
      }
    }
    // stage B second: W[:, s*128 .. s*128+128)
#pragma unroll
    for (int cc = 0; cc < 8; ++cc) {
      int ch = cc*256 + tid;
      int r = ch >> 4, h0 = (ch & 15) * 8;
      *(short8*)&Bsl[r][h0] = *(const short8*)&W[(size_t)r*KTOT + s*128 + h0];
    }
    bar_lgkm();   // Asl/Bsl visible
#pragma unroll
    for (int ks = 0; ks < 4; ++ks) {
      int k0 = ks*32 + lq*8;
      short8 a[2], bb[8];
#pragma unroll
      for (int i = 0; i < 2; ++i) a[i] = *(const short8*)&Asl[m0 + i*16 + lm][k0];
#pragma unroll
      for (int j = 0; j < 8; ++j) bb[j] = *(const short8*)&Bsl[j*16 + lm][k0];
#pragma unroll
      for (int i = 0; i < 2; ++i)
#pragma unroll
        for (int j = 0; j < 8; ++j)
          acc[i][j] = __builtin_amdgcn_mfma_f32_16x16x32_bf16(a[i], bb[j], acc[i][j], 0, 0, 0);
    }
  }
#pragma unroll
  for (int i = 0; i < 2; ++i)
#pragma unroll
    for (int j = 0; j < 8; ++j)
#pragma unroll
      for (int r = 0; r < 4; ++r)
        y[(size_t)(row0 + m0 + i*16 + lq*4 + r)*HOUT + j*16 + lm] = acc[i][j][r];
}

// --------------------------------------------------------------------------
extern "C" void kernel_launch(void* const* d_in, const int* in_sizes, int n_in,
                              void* d_out, int out_size, void* d_ws, size_t ws_size,
                              hipStream_t stream) {
  const float* u         = (const float*)d_in[0];
  const float* nu_log    = (const float*)d_in[1];
  const float* theta_log = (const float*)d_in[2];
  const float* gamma_log = (const float*)d_in[3];
  const float* B_re      = (const float*)d_in[4];
  const float* B_im      = (const float*)d_in[5];
  const float* C_re      = (const float*)d_in[6];
  const float* C_im      = (const float*)d_in[7];
  const float* Dm        = (const float*)d_in[8];
  float* y = (float*)d_out;
  char* ws = (char*)d_ws;

  size_t off = 0;
  float* lamre = (float*)(ws + off);            off += 1024;
  float* lamim = (float*)(ws + off);            off += 1024;
  unsigned* lamPk = (unsigned*)(ws + off);      off += 32768;       // 32x256 u32
  unsigned short* Wb = (unsigned short*)(ws + off); off += 131072;  // 512x128 bf16
  unsigned short* W  = (unsigned short*)(ws + off); off += 163840;  // 128x640 bf16
  unsigned short* preL = (unsigned short*)(ws + off); off += (size_t)ROWS*NPRE*2; // 64 MB
  float* S_re = (float*)(ws + off);             off += 2097152;
  float* S_im = (float*)(ws + off);             off += 2097152;
  unsigned* X0Pk = (unsigned*)(ws + off);       off += 2097152;     // 2048x256 u32

  k_prep<<<320, 256, 0, stream>>>(nu_log, theta_log, gamma_log, B_re, B_im,
                                  C_re, C_im, Dm, lamre, lamim, lamPk, Wb, W);
  k_bu<<<ROWS/128, 256, 0, stream>>>(u, Wb, lamre, lamim, preL, S_re, S_im);
  k_scan<<<64, 64, 0, stream>>>(S_re, S_im, lamre, lamim, X0Pk);
  k_out2<<<ROWS/128, 256, 0, stream>>>(preL, u, W, lamPk, X0Pk, y);
}